// Round 10
// baseline (175.975 us; speedup 1.0000x reference)
//
#include <hip/hip_runtime.h>
#include <math.h>

// RelationalAttention: N=20000 nodes, E=320000 edges, D=128, H=2 (H*D=256), R=3.
// 4-dispatch pipeline:
//   K1 cvt6: f32->f16 (nf, [WQ;WK;WV], WO) + zero cnt
//   K2 proj||scatter: fused f16 MFMA GEMM qkv = nfb @ [WQ;WK;WV]^T (XCD-swizzled)
//      running concurrently with padded-mailbox edge scatter
//   K3 attn: per-dst-wave, depth-2 software-pipelined gather (codes preloaded
//      into registers, K/V of t+1,t+2 in flight while computing t)
//   K4 out = z @ WO^T (f32 out)
// Padded mailbox (MAXDEG=64): deg ~ Binomial(320k,5e-5) => P(deg>64) < 1e-22.

typedef _Float16 f16x8 __attribute__((ext_vector_type(8)));
typedef float f32x4 __attribute__((ext_vector_type(4)));

#define MAXDEG 64

__device__ __forceinline__ ushort f2h(float f) {  // RNE
  return __builtin_bit_cast(ushort, (_Float16)f);
}

// ---------------- K1: f32 -> f16 conversion + cnt zeroing (6 segments) ----------------

__global__ __launch_bounds__(256) void cvt6_kernel(
    const float* __restrict__ s0, ushort* __restrict__ d0, int n0,
    const float* __restrict__ s1, ushort* __restrict__ d1, int n1,
    const float* __restrict__ s2, ushort* __restrict__ d2, int n2,
    const float* __restrict__ s3, ushort* __restrict__ d3, int n3,
    const float* __restrict__ s4, ushort* __restrict__ d4, int n4,
    ushort* __restrict__ d5, int n5,                    // zero-fill segment (cnt)
    int b1, int b2, int b3, int b4, int b5) {
  int b = blockIdx.x;
  const float* s; ushort* d; int n, lb;
  if (b < b1)      { s = s0; d = d0; n = n0; lb = b; }
  else if (b < b2) { s = s1; d = d1; n = n1; lb = b - b1; }
  else if (b < b3) { s = s2; d = d2; n = n2; lb = b - b2; }
  else if (b < b4) { s = s3; d = d3; n = n3; lb = b - b3; }
  else if (b < b5) { s = s4; d = d4; n = n4; lb = b - b4; }
  else             { s = nullptr; d = d5; n = n5; lb = b - b5; }
  int i = lb * 1024 + threadIdx.x * 4;
  if (i + 4 <= n) {
    ushort4 o;
    if (s) {
      float4 v = *(const float4*)&s[i];
      o.x = f2h(v.x); o.y = f2h(v.y); o.z = f2h(v.z); o.w = f2h(v.w);
    } else {
      o.x = 0; o.y = 0; o.z = 0; o.w = 0;
    }
    *(ushort4*)&d[i] = o;
  }
}

// ---------------- shared GEMM body: C[m][n] = sum_k A[m][k] * B[n][k] ----------------
// 128xBN tile, 256 threads (4 waves, 2x2; each wave 64 x BN/2), BK=64.
// K % 64 == 0, Ncols % BN == 0. LDS granule layout [k8][m] / [k8][n] (16B granules):
// staging (global_load_lds, linear dest + permuted per-lane source) and fragment
// ds_read_b128 both conflict-free. Layouts HW-validated rounds 6-9.

template <int K, int BN, typename OutT>
__device__ __forceinline__ void gemm_body(const ushort* __restrict__ A,
                                          const ushort* __restrict__ B,
                                          OutT* __restrict__ C, int M, int Ncols,
                                          int bx, int by, uint4* Ag, uint4* Bg) {
  constexpr int FN = BN / 32;          // B fragments per wave per k-half
  constexpr int NBI = BN / 32;         // B staging instructions per k-step
  const int t = threadIdx.x;
  const int lane = t & 63;
  const int w = t >> 6;
  const int wr = w >> 1, wc = w & 1;   // wave quadrant: rows wr*64, cols wc*(BN/2)
  const int m0 = bx * 128;
  const int n0 = by * BN;

  f32x4 acc[4][FN] = {};               // [fm][fn] 16x16 fragments

  for (int kc = 0; kc < K; kc += 64) {
    if (kc) __syncthreads();
    #pragma unroll
    for (int i = 0; i < 4; ++i) {      // A tile: 1024 granules
      int gbase = (w * 4 + i) * 64;
      int gi = gbase + lane;
      int k8 = gi >> 7, mm = gi & 127;
      int gm = m0 + mm; if (gm >= M) gm = M - 1;    // clamp tail (C-write guarded)
      const ushort* srcA = A + (size_t)gm * K + kc + k8 * 8;
      __builtin_amdgcn_global_load_lds(
          (const __attribute__((address_space(1))) void*)srcA,
          (__attribute__((address_space(3))) void*)(Ag + gbase), 16, 0, 0);
    }
    #pragma unroll
    for (int i = 0; i < NBI; ++i) {    // B tile: 8*BN granules
      int gbase = (w * NBI + i) * 64;
      int gi = gbase + lane;
      int k8 = gi / BN, nn = gi & (BN - 1);
      const ushort* srcB = B + (size_t)(n0 + nn) * K + kc + k8 * 8;
      __builtin_amdgcn_global_load_lds(
          (const __attribute__((address_space(1))) void*)srcB,
          (__attribute__((address_space(3))) void*)(Bg + gbase), 16, 0, 0);
    }
    __syncthreads();   // drains vmcnt before barrier => tiles ready

    #pragma unroll
    for (int ks = 0; ks < 2; ++ks) {
      int k8 = ks * 4 + (lane >> 4);
      f16x8 af[4], bfr[FN];
      #pragma unroll
      for (int f = 0; f < 4; ++f)
        af[f] = __builtin_bit_cast(f16x8, Ag[k8 * 128 + wr * 64 + f * 16 + (lane & 15)]);
      #pragma unroll
      for (int f = 0; f < FN; ++f)
        bfr[f] = __builtin_bit_cast(f16x8, Bg[k8 * BN + wc * (BN / 2) + f * 16 + (lane & 15)]);
      #pragma unroll
      for (int fm = 0; fm < 4; ++fm)
        #pragma unroll
        for (int fn = 0; fn < FN; ++fn)
          acc[fm][fn] =
              __builtin_amdgcn_mfma_f32_16x16x32_f16(af[fm], bfr[fn], acc[fm][fn], 0, 0, 0);
    }
  }

  // C/D layout (dtype-independent, HW-validated): col = lane&15, row = (lane>>4)*4 + reg
  #pragma unroll
  for (int fm = 0; fm < 4; ++fm) {
    #pragma unroll
    for (int r = 0; r < 4; ++r) {
      int m = m0 + wr * 64 + fm * 16 + (lane >> 4) * 4 + r;
      if (m < M) {
        #pragma unroll
        for (int fn = 0; fn < FN; ++fn) {
          int n = n0 + wc * (BN / 2) + fn * 16 + (lane & 15);
          float v = acc[fm][fn][r];
          if constexpr (sizeof(OutT) == 2)
            C[(size_t)m * Ncols + n] = (OutT)f2h(v);
          else
            C[(size_t)m * Ncols + n] = (OutT)v;
        }
      }
    }
  }
}

template <int K, int BN, typename OutT>
__global__ __launch_bounds__(256) void gemm_mfma(const ushort* __restrict__ A,
                                                 const ushort* __restrict__ B,
                                                 OutT* __restrict__ C, int M, int Ncols) {
  __shared__ uint4 Ag[1024];
  __shared__ uint4 Bg[8 * BN];
  gemm_body<K, BN, OutT>(A, B, C, M, Ncols, blockIdx.x, blockIdx.y, Ag, Bg);
}

// ---------------- K2: fused projection GEMM || edge scatter ----------------

__global__ __launch_bounds__(256) void proj_scatter(
    const ushort* __restrict__ A, const ushort* __restrict__ B,
    ushort* __restrict__ C, int M,
    const int* __restrict__ dst, const int* __restrict__ src,
    const int* __restrict__ rel, int* __restrict__ cnt,
    int* __restrict__ slots, int E, int PB) {
  __shared__ uint4 Ag[1024];
  __shared__ uint4 Bg[2048];   // BN=256
  int bid = blockIdx.x;
  if (bid >= PB) {
    int i = (bid - PB) * 256 + threadIdx.x;
    if (i < E) {
      int d = dst[i];
      int pos = atomicAdd(&cnt[d], 1);
      if (pos < MAXDEG)
        slots[(size_t)d * MAXDEG + pos] = src[i] * 1792 + 256 + rel[i] * 256;
    }
    return;
  }
  // bijective XCD chunk swizzle (nwg = PB, 8 XCDs): orig -> contiguous logical chunk
  int q = PB >> 3, r = PB & 7;
  int xcd = bid & 7, rest = bid >> 3;
  int wg = (xcd < r ? xcd * (q + 1) : r * (q + 1) + (xcd - r) * q) + rest;
  int bx = wg / 7, by = wg % 7;        // A-sharing group (7 col-blocks) contiguous
  gemm_body<128, 256, ushort>(A, B, C, M, 1792, bx, by, Ag, Bg);
}

// ---------------- K3: per-dst attention (depth-2 pipelined gather) ----------------
// One wave per node. Lane l: ep = l>>5 (edge-of-pair), (l&31)*8 = hd*128 + sub*8.
// Codes preloaded (one coalesced lane-load, broadcast via shfl). Rotating depth-2
// pipeline: K/V for t+1 and t+2 in flight while computing t. Loop count
// nt = ceil(m/2) is wave-uniform => no divergence; invalid slots read the node's
// own L1-hot q row and are predicated to numer=0 (exact denominator semantics).

__global__ __launch_bounds__(256) void attn_kernel(
    const ushort* __restrict__ qkv, const int* __restrict__ cnt,
    const int* __restrict__ slots, ushort* __restrict__ z, int N) {
  int w = threadIdx.x >> 6;
  int l = threadIdx.x & 63;
  int n = blockIdx.x * 4 + w;
  if (n >= N) return;

  const int ep = l >> 5, off_hs = (l & 31) * 8;   // hd*128 + sub*8
  const int qbase = n * 1792;                     // L1-hot dummy target

  f16x8 qv = __builtin_bit_cast(f16x8, *(const uint4*)(qkv + (size_t)qbase + off_hs));
  float qf[8];
  #pragma unroll
  for (int j = 0; j < 8; ++j) qf[j] = (float)qv[j];

  int m = cnt[n]; if (m > MAXDEG) m = MAXDEG;
  // preload this node's mailbox codes: one coalesced 4B lane-load
  int mycode = (l < m) ? slots[(size_t)n * MAXDEG + l] : qbase;

  const int nt = (m + 1) >> 1;                    // wave-uniform trip count

  // fetch helper: K/V uint4 pair for edge index idx (= 2t+ep), sanitized
  auto fetch = [&](int t, uint4& kk, uint4& vv) {
    int idx = 2 * t + ep;
    int c = __shfl(mycode, idx & 63);
    c = (idx < m) ? c : qbase;                    // dummy -> own q row (L1-hot)
    const ushort* kp = qkv + (size_t)c + off_hs;
    kk = *(const uint4*)kp;
    vv = *(const uint4*)(kp + 768);
  };

  float acc[8] = {};
  float denom = 0.f;

  uint4 k0, v0, k1, v1;
  if (nt > 0) {
    fetch(0, k0, v0);
    fetch(1, k1, v1);
  }
  for (int t = 0; t < nt; ++t) {
    uint4 k2, v2;
    fetch(t + 2, k2, v2);                         // issue 2-ahead loads
    // compute on (k0, v0) = edge 2t+ep
    bool valid = (2 * t + ep) < m;
    f16x8 k8 = __builtin_bit_cast(f16x8, k0);
    f16x8 v8 = __builtin_bit_cast(f16x8, v0);
    float p = 0.f;
    #pragma unroll
    for (int j = 0; j < 8; ++j) p += qf[j] * (float)k8[j];
    p += __shfl_xor(p, 1);
    p += __shfl_xor(p, 2);
    p += __shfl_xor(p, 4);
    p += __shfl_xor(p, 8);                        // reduced over the 16-lane group
    float s = p * 0.0625f;                        // / sqrt(H*D)=16
    float rr = fmaxf(s, 0.0f);
    float numer = valid ? (rr * rr + 1e-10f) : 0.f;
    denom += numer;
    #pragma unroll
    for (int j = 0; j < 8; ++j) acc[j] += numer * (float)v8[j];
    // rotate pipeline (static register moves)
    k0 = k1; v0 = v1; k1 = k2; v1 = v2;
  }
  // combine the two edge groups (lane ^ 32 has same (hd,sub), other edges)
  #pragma unroll
  for (int j = 0; j < 8; ++j) acc[j] += __shfl_xor(acc[j], 32);
  denom += __shfl_xor(denom, 32);

  float inv = (m > 0) ? (1.0f / denom) : 0.0f;
  if (l < 32) {
    f16x8 ov;
    #pragma unroll
    for (int j = 0; j < 8; ++j) ov[j] = (_Float16)(acc[j] * inv);
    *(uint4*)(z + (size_t)n * 256 + off_hs) = __builtin_bit_cast(uint4, ov);
  }
}

// ---------------- launch ----------------

extern "C" void kernel_launch(void* const* d_in, const int* in_sizes, int n_in,
                              void* d_out, int out_size, void* d_ws, size_t ws_size,
                              hipStream_t stream) {
  const float* nf = (const float*)d_in[0];
  const float* WQ = (const float*)d_in[1];   // [256,128]
  const float* WK = (const float*)d_in[2];   // [3,256,128] == [768,128]
  const float* WV = (const float*)d_in[3];
  const float* WO = (const float*)d_in[4];   // [128,256]
  const int* esrc = (const int*)d_in[5];
  const int* edst = (const int*)d_in[6];
  const int* erel = (const int*)d_in[7];
  float* out = (float*)d_out;

  const int M = in_sizes[0] / 128;  // 20000 nodes
  const int E = in_sizes[5];        // 320000 edges

  char* ws = (char*)d_ws;
  size_t off = 0;
  auto alloc = [&](size_t bytes) -> void* {
    void* p = ws + off;
    off = (off + bytes + 255) & ~(size_t)255;
    return p;
  };
  ushort* nfb  = (ushort*)alloc((size_t)M * 128 * 2);
  ushort* wall = (ushort*)alloc((size_t)1792 * 128 * 2);  // [WQ;WK;WV] rows
  ushort* wob  = (ushort*)alloc((size_t)128 * 256 * 2);
  ushort* qkv  = (ushort*)alloc((size_t)M * 1792 * 2);    // q | keys | vals per row
  ushort* z    = (ushort*)alloc((size_t)M * 256 * 2);
  int* cnt     = (int*)alloc((size_t)M * 4);
  int* slots   = (int*)alloc((size_t)M * MAXDEG * 4);

  // --- K1: conversions + cnt zeroing, one launch ---
  int c0 = M * 128, c1 = 256 * 128, c2 = 768 * 128, c3 = 768 * 128, c4 = 128 * 256;
  int c5 = 2 * M;  // cnt as ushorts (M ints)
  int nb0 = (c0 + 1023) / 1024, nb1 = (c1 + 1023) / 1024, nb2 = (c2 + 1023) / 1024,
      nb3 = (c3 + 1023) / 1024, nb4 = (c4 + 1023) / 1024, nb5 = (c5 + 1023) / 1024;
  cvt6_kernel<<<nb0 + nb1 + nb2 + nb3 + nb4 + nb5, 256, 0, stream>>>(
      nf, nfb, c0,
      WQ, wall, c1,
      WK, wall + (size_t)256 * 128, c2,
      WV, wall + (size_t)1024 * 128, c3,
      WO, wob, c4,
      (ushort*)cnt, c5,
      nb0, nb0 + nb1, nb0 + nb1 + nb2, nb0 + nb1 + nb2 + nb3,
      nb0 + nb1 + nb2 + nb3 + nb4);

  // --- K2: fused projection GEMM || mailbox scatter ---
  int mb = (M + 127) / 128;
  int PB = mb * 7;                 // 128x256 tiles over Ncols=1792
  int EB = (E + 255) / 256;
  proj_scatter<<<PB + EB, 256, 0, stream>>>(nfb, wall, qkv, M,
                                            edst, esrc, erel, cnt, slots, E, PB);

  // --- K3: per-dst attention ---
  attn_kernel<<<(M + 3) / 4, 256, 0, stream>>>(qkv, cnt, slots, z, M);

  // --- K4: out = z @ WO^T (f32 output) ---
  gemm_mfma<256, 128, float><<<dim3(mb, 1), 256, 0, stream>>>(z, wob, out, M, 128);
}